// Round 3
// baseline (151.109 us; speedup 1.0000x reference)
//
#include <hip/hip_runtime.h>
#include <math.h>

#define NBATCH 128
#define S 7
#define NBOX 2
#define NCLS 20
#define CH 30
#define N 12544              // 128*7*7*2
#define JCHUNK 1568
#define NJCH 8               // JCHUNK*NJCH == N
#define THRNMS 0.3

// f32 sigmoid cascade, mirroring numpy float32 ops:
//   e = expf(-x)  (f64 exp rounded once -> correctly-rounded f32 exp)
//   s = 1.0f / (1.0f + e)   (f32 add, f32 div)
__device__ __forceinline__ float sigf(float x) {
    float e = (float)exp(-(double)x);
    return 1.0f / (1.0f + e);
}

// ---------------- decode: per-box record + f32-cascade sort key ----------------
__global__ __launch_bounds__(256) void k_decode(
    const float* __restrict__ p,
    unsigned int* __restrict__ key,
    float* __restrict__ score,
    float* __restrict__ box,
    int* __restrict__ meta,
    unsigned int* __restrict__ rank)
{
    int i = blockIdx.x * 256 + threadIdx.x;
    if (i >= N) return;
    int j    = i & 1;
    int cell = i >> 1;
    int x    = cell % S;
    int y    = (cell / S) % S;
    int b    = cell / (S * S);
    const float* pc = p + cell * CH;

    float tx = pc[j * 4 + 0], ty = pc[j * 4 + 1];
    float tw = pc[j * 4 + 2], th = pc[j * 4 + 3];
    float craw = pc[8 + j];

    // first-occurrence argmax over f32-cascade sigmoid(class logits),
    // matching np.argmax on the f32 cls array
    float best = sigf(pc[10]);
    int lab = 0;
#pragma unroll
    for (int c = 1; c < NCLS; ++c) {
        float v = sigf(pc[10 + c]);
        if (v > best) { best = v; lab = c; }
    }
    int label = lab + 1;

    // f32 box geometry in numpy op order
    float sx = sigf(tx), sy = sigf(ty);
    float cx = (sx + (float)x) / 7.0f;
    float cy = (sy + (float)y) / 7.0f;
    float hw = tw / 2.0f, hh = th / 2.0f;
    float l = cx - hw, t = cy - hh, r = cx + hw, bt = cy + hh;

    float sc = sigf(craw);
    bool valid = sc > 0.5f;

    // positive f32 bits are monotone as u32; invalid -> 0 (sorts last; ties
    // broken by descending index = argsort(stable)[::-1] semantics)
    unsigned int k = valid ? __float_as_uint(sc) : 0u;
    key[i] = k;
    score[i] = sc;
    box[i * 4 + 0] = l; box[i * 4 + 1] = t;
    box[i * 4 + 2] = r; box[i * 4 + 3] = bt;
    meta[i] = (valid ? 0x8000 : 0) | (b << 5) | label;
    rank[i] = 0u;   // init for atomic partial-rank accumulation
}

// ---------------- rank: descending score, tie -> descending index ----------------
__global__ __launch_bounds__(256) void k_rank(
    const unsigned int* __restrict__ key,
    unsigned int* __restrict__ rank)
{
    __shared__ unsigned int lk[JCHUNK];
    int base = blockIdx.y * JCHUNK;
    for (int t = threadIdx.x; t < JCHUNK; t += 256) lk[t] = key[base + t];
    __syncthreads();

    int i = blockIdx.x * 256 + threadIdx.x;   // grid is exactly 49*256 == N
    unsigned int ki = key[i];
    unsigned int cnt = 0;
    for (int u = 0; u < JCHUNK; ++u) {
        unsigned int kj = lk[u];
        int jg = base + u;
        cnt += (unsigned int)((kj > ki) || (kj == ki && jg > i));
    }
    atomicAdd(&rank[i], cnt);
}

// ---------------- scatter into sorted order ----------------
__global__ __launch_bounds__(256) void k_scatter(
    const unsigned int* __restrict__ rank,
    const float* __restrict__ score,
    const float* __restrict__ box,
    const int* __restrict__ meta,
    int* __restrict__ smeta,
    float* __restrict__ sbox,
    float* __restrict__ out)
{
    int i = blockIdx.x * 256 + threadIdx.x;
    if (i >= N) return;
    unsigned int pos = rank[i];
    int m = meta[i];
    int b = (m >> 5) & 0x7F;
    int label = m & 31;

    float l = box[i * 4 + 0], t = box[i * 4 + 1];
    float r = box[i * 4 + 2], bt = box[i * 4 + 3];

    out[pos] = (float)b;                       // idsb_s
    out[N + pos * 4 + 0] = l;                  // boxes_s
    out[N + pos * 4 + 1] = t;
    out[N + pos * 4 + 2] = r;
    out[N + pos * 4 + 3] = bt;
    out[5 * N + pos] = (float)label;           // labs_s
    out[6 * N + pos] = score[i];               // scores_s
    out[7 * N + pos] = 0.0f;                   // keep default false

    smeta[pos] = m;
    sbox[pos * 4 + 0] = l; sbox[pos * 4 + 1] = t;
    sbox[pos * 4 + 2] = r; sbox[pos * 4 + 3] = bt;
}

// ---------------- greedy NMS: one wave per batch ----------------
__global__ __launch_bounds__(64) void k_nms(
    const int* __restrict__ smeta,
    const float* __restrict__ sbox,
    float* __restrict__ keepout)
{
    int b = blockIdx.x;
    int lane = threadIdx.x;
    __shared__ int list[104];
    __shared__ int lab[104];
    __shared__ int sup[104];
    __shared__ float bx[104][4];

    // gather this batch's valid members in sorted order (valid are a prefix)
    int cnt = 0;
    for (int c = 0; c < (N + 63) / 64; ++c) {
        int pos = c * 64 + lane;
        int m = (pos < N) ? smeta[pos] : 0;
        bool valid = (m & 0x8000) != 0;
        unsigned long long vb = __ballot(valid);
        if (vb == 0ull) break;                    // past the valid prefix
        bool member = valid && (((m >> 5) & 0x7F) == b);
        unsigned long long mb = __ballot(member);
        if (member) {
            int idx = cnt + __popcll(mb & ((1ull << lane) - 1ull));
            list[idx] = pos;
            lab[idx] = m & 31;
        }
        cnt += __popcll(mb);
    }
    int k = cnt;                                  // <= 98 structurally
    __syncthreads();

    for (int t = lane; t < k; t += 64) {
        int pos = list[t];
        bx[t][0] = sbox[pos * 4 + 0];
        bx[t][1] = sbox[pos * 4 + 1];
        bx[t][2] = sbox[pos * 4 + 2];
        bx[t][3] = sbox[pos * 4 + 3];
        sup[t] = 0;
    }
    __syncthreads();

    for (int i = 0; i < k; ++i) {
        __syncthreads();
        if (sup[i]) continue;                     // uniform (broadcast read)
        float li = bx[i][0], ti = bx[i][1], ri = bx[i][2], bi = bx[i][3];
        float areai = (ri - li) * (bi - ti);      // f32, np op order
        int labi = lab[i];
        for (int jj = i + 1 + lane; jj < k; jj += 64) {
            if (lab[jj] != labi) continue;
            float lj = bx[jj][0], tj = bx[jj][1], rj = bx[jj][2], bj = bx[jj][3];
            float lt0 = fmaxf(li, lj), lt1 = fmaxf(ti, tj);
            float rb0 = fminf(ri, rj), rb1 = fminf(bi, bj);
            float w = rb0 - lt0; if (w < 0.0f) w = 0.0f;
            float h = rb1 - lt1; if (h < 0.0f) h = 0.0f;
            float inter = w * h;
            float areaj = (rj - lj) * (bj - tj);
            float uni = areai + areaj - inter;
            // final divide+compare in f64 (robust to numpy promotion variant)
            double iou = (double)inter / fmax((double)uni, 1e-9);
            if (iou > THRNMS) sup[jj] = 1;
        }
    }
    __syncthreads();

    for (int t = lane; t < k; t += 64) {
        if (!sup[t]) keepout[list[t]] = 1.0f;
    }
}

extern "C" void kernel_launch(void* const* d_in, const int* in_sizes, int n_in,
                              void* d_out, int out_size, void* d_ws, size_t ws_size,
                              hipStream_t stream)
{
    const float* p = (const float*)d_in[0];

    char* w = (char*)d_ws;
    unsigned int* key = (unsigned int*)w;              w += (size_t)N * 4;
    float* score = (float*)w;                          w += (size_t)N * 4;
    float* box   = (float*)w;                          w += (size_t)N * 16;
    float* sbox  = (float*)w;                          w += (size_t)N * 16;
    int* meta    = (int*)w;                            w += (size_t)N * 4;
    int* smeta   = (int*)w;                            w += (size_t)N * 4;
    unsigned int* rank = (unsigned int*)w;             w += (size_t)N * 4;

    float* out = (float*)d_out;

    k_decode <<<dim3(49),        dim3(256), 0, stream>>>(p, key, score, box, meta, rank);
    k_rank   <<<dim3(49, NJCH),  dim3(256), 0, stream>>>(key, rank);
    k_scatter<<<dim3(49),        dim3(256), 0, stream>>>(rank, score, box, meta, smeta, sbox, out);
    k_nms    <<<dim3(NBATCH),    dim3(64),  0, stream>>>(smeta, sbox, out + 7 * N);
}

// Round 4
// 148.162 us; speedup vs baseline: 1.0199x; 1.0199x over previous
//
#include <hip/hip_runtime.h>
#include <math.h>

#define NBATCH 128
#define S 7
#define NCLS 20
#define CH 30
#define N 12544              // 128*7*7*2
#define PERB 98              // boxes per batch (7*7*2)
#define JCHUNK 1568
#define NJCH 8               // JCHUNK*NJCH == N
#define MAXK 112             // >= PERB, slot stride per batch
#define THRNMS 0.3

// f32 sigmoid cascade, mirroring numpy float32 ops:
//   e = expf(-x)  (f64 exp rounded once -> correctly-rounded f32 exp)
//   s = 1.0f / (1.0f + e)
__device__ __forceinline__ float sigf(float x) {
    float e = (float)exp(-(double)x);
    return 1.0f / (1.0f + e);
}

// ---------------- zero the per-batch counters (ws is poisoned 0xAA) --------
__global__ void k_zero(unsigned int* __restrict__ batchcnt) {
    batchcnt[threadIdx.x] = 0u;
}

// ---------------- decode: per-box record + f32-cascade sort key ----------------
__global__ __launch_bounds__(256) void k_decode(
    const float* __restrict__ p,
    unsigned int* __restrict__ key,
    float* __restrict__ score,
    float* __restrict__ box,
    int* __restrict__ meta,
    unsigned int* __restrict__ rank,
    unsigned int* __restrict__ brank,
    unsigned int* __restrict__ batchcnt)
{
    int i = blockIdx.x * 256 + threadIdx.x;
    if (i >= N) return;
    int j    = i & 1;
    int cell = i >> 1;
    int x    = cell % S;
    int y    = (cell / S) % S;
    int b    = cell / (S * S);
    const float* pc = p + cell * CH;

    float tx = pc[j * 4 + 0], ty = pc[j * 4 + 1];
    float tw = pc[j * 4 + 2], th = pc[j * 4 + 3];
    float craw = pc[8 + j];

    // first-occurrence argmax over f32-cascade sigmoid(class logits)
    float best = sigf(pc[10]);
    int lab = 0;
#pragma unroll
    for (int c = 1; c < NCLS; ++c) {
        float v = sigf(pc[10 + c]);
        if (v > best) { best = v; lab = c; }
    }
    int label = lab + 1;

    // f32 box geometry in numpy op order
    float sx = sigf(tx), sy = sigf(ty);
    float cx = (sx + (float)x) / 7.0f;
    float cy = (sy + (float)y) / 7.0f;
    float hw = tw / 2.0f, hh = th / 2.0f;
    float l = cx - hw, t = cy - hh, r = cx + hw, bt = cy + hh;

    float sc = sigf(craw);
    bool valid = sc > 0.5f;

    // positive f32 bits monotone as u32; invalid -> 0 (sorts last; ties broken
    // by descending index = argsort(stable)[::-1] semantics)
    unsigned int k = valid ? __float_as_uint(sc) : 0u;
    key[i] = k;
    score[i] = sc;
    box[i * 4 + 0] = l; box[i * 4 + 1] = t;
    box[i * 4 + 2] = r; box[i * 4 + 3] = bt;
    meta[i] = (valid ? 0x8000 : 0) | (b << 5) | label;
    rank[i] = 0u;
    brank[i] = 0u;
    if (valid) atomicAdd(&batchcnt[b], 1u);
}

// ---- rank: global rank + within-batch rank (desc score, tie desc index) ----
__global__ __launch_bounds__(256) void k_rank(
    const unsigned int* __restrict__ key,
    unsigned int* __restrict__ rank,
    unsigned int* __restrict__ brank)
{
    __shared__ uint2 lkb[JCHUNK];         // {key, batch}
    int base = blockIdx.y * JCHUNK;
    for (int t = threadIdx.x; t < JCHUNK; t += 256) {
        int jg = base + t;
        lkb[t] = make_uint2(key[jg], (unsigned int)(jg / PERB));
    }
    __syncthreads();

    int i = blockIdx.x * 256 + threadIdx.x;   // grid.x*256 == N exactly
    unsigned int ki = key[i];
    unsigned int bi = (unsigned int)(i / PERB);
    unsigned int cnt = 0, bcnt = 0;
    for (int u = 0; u < JCHUNK; ++u) {
        uint2 v = lkb[u];
        int jg = base + u;
        unsigned int c = (unsigned int)((v.x > ki) || (v.x == ki && jg > i));
        cnt += c;
        bcnt += c & (unsigned int)(v.y == bi);
    }
    atomicAdd(&rank[i], cnt);
    atomicAdd(&brank[i], bcnt);
}

// ---------------- scatter into sorted order + per-batch member lists ----------------
__global__ __launch_bounds__(256) void k_scatter(
    const unsigned int* __restrict__ rank,
    const unsigned int* __restrict__ brank,
    const float* __restrict__ score,
    const float* __restrict__ box,
    const int* __restrict__ meta,
    float4* __restrict__ mbox,
    int* __restrict__ mlab,
    int* __restrict__ mpos,
    float* __restrict__ out)
{
    int i = blockIdx.x * 256 + threadIdx.x;
    if (i >= N) return;
    unsigned int pos = rank[i];
    int m = meta[i];
    int b = (m >> 5) & 0x7F;
    int label = m & 31;

    float l = box[i * 4 + 0], t = box[i * 4 + 1];
    float r = box[i * 4 + 2], bt = box[i * 4 + 3];

    out[pos] = (float)b;                       // idsb_s
    out[N + pos * 4 + 0] = l;                  // boxes_s
    out[N + pos * 4 + 1] = t;
    out[N + pos * 4 + 2] = r;
    out[N + pos * 4 + 3] = bt;
    out[5 * N + pos] = (float)label;           // labs_s
    out[6 * N + pos] = score[i];               // scores_s
    out[7 * N + pos] = 0.0f;                   // keep default false

    if (m & 0x8000) {                          // valid: emit compacted member
        int slot = b * MAXK + (int)brank[i];   // brank < kb <= 98 (all same-batch
        mbox[slot] = make_float4(l, t, r, bt); //  elements ahead of a valid one
        mlab[slot] = label;                    //  are themselves valid)
        mpos[slot] = (int)pos;
    }
}

// ---------------- greedy NMS: one wave per batch, gather-free ----------------
__global__ __launch_bounds__(64) void k_nms(
    const unsigned int* __restrict__ batchcnt,
    const float4* __restrict__ mbox,
    const int* __restrict__ mlab,
    const int* __restrict__ mpos,
    float* __restrict__ keepout)
{
    int b = blockIdx.x;
    int lane = threadIdx.x;
    __shared__ float bx[MAXK][4];
    __shared__ int lab[MAXK];
    __shared__ int list[MAXK];
    __shared__ int sup[MAXK];

    int k = (int)batchcnt[b];                  // <= 98 structurally
    for (int t = lane; t < k; t += 64) {
        float4 v = mbox[b * MAXK + t];
        bx[t][0] = v.x; bx[t][1] = v.y; bx[t][2] = v.z; bx[t][3] = v.w;
        lab[t] = mlab[b * MAXK + t];
        list[t] = mpos[b * MAXK + t];
        sup[t] = 0;
    }
    __syncthreads();

    for (int i = 0; i < k; ++i) {
        __syncthreads();
        if (sup[i]) continue;                  // uniform broadcast read
        float li = bx[i][0], ti = bx[i][1], ri = bx[i][2], bi = bx[i][3];
        float areai = (ri - li) * (bi - ti);
        int labi = lab[i];
        for (int jj = i + 1 + lane; jj < k; jj += 64) {
            if (lab[jj] != labi) continue;
            float lj = bx[jj][0], tj = bx[jj][1], rj = bx[jj][2], bj = bx[jj][3];
            float lt0 = fmaxf(li, lj), lt1 = fmaxf(ti, tj);
            float rb0 = fminf(ri, rj), rb1 = fminf(bi, bj);
            float w = rb0 - lt0; if (w < 0.0f) w = 0.0f;
            float h = rb1 - lt1; if (h < 0.0f) h = 0.0f;
            float inter = w * h;
            float areaj = (rj - lj) * (bj - tj);
            float uni = areai + areaj - inter;
            double iou = (double)inter / fmax((double)uni, 1e-9);
            if (iou > THRNMS) sup[jj] = 1;
        }
    }
    __syncthreads();

    for (int t = lane; t < k; t += 64) {
        if (!sup[t]) keepout[list[t]] = 1.0f;
    }
}

extern "C" void kernel_launch(void* const* d_in, const int* in_sizes, int n_in,
                              void* d_out, int out_size, void* d_ws, size_t ws_size,
                              hipStream_t stream)
{
    const float* p = (const float*)d_in[0];

    char* w = (char*)d_ws;
    float4* mbox = (float4*)w;                         w += (size_t)NBATCH * MAXK * 16;
    unsigned int* key = (unsigned int*)w;              w += (size_t)N * 4;
    float* score = (float*)w;                          w += (size_t)N * 4;
    float* box   = (float*)w;                          w += (size_t)N * 16;
    int* meta    = (int*)w;                            w += (size_t)N * 4;
    unsigned int* rank  = (unsigned int*)w;            w += (size_t)N * 4;
    unsigned int* brank = (unsigned int*)w;            w += (size_t)N * 4;
    int* mlab    = (int*)w;                            w += (size_t)NBATCH * MAXK * 4;
    int* mpos    = (int*)w;                            w += (size_t)NBATCH * MAXK * 4;
    unsigned int* batchcnt = (unsigned int*)w;         w += (size_t)NBATCH * 4;

    float* out = (float*)d_out;

    k_zero   <<<dim3(1),         dim3(NBATCH), 0, stream>>>(batchcnt);
    k_decode <<<dim3(49),        dim3(256), 0, stream>>>(p, key, score, box, meta,
                                                         rank, brank, batchcnt);
    k_rank   <<<dim3(49, NJCH),  dim3(256), 0, stream>>>(key, rank, brank);
    k_scatter<<<dim3(49),        dim3(256), 0, stream>>>(rank, brank, score, box, meta,
                                                         mbox, mlab, mpos, out);
    k_nms    <<<dim3(NBATCH),    dim3(64),  0, stream>>>(batchcnt, mbox, mlab, mpos,
                                                         out + 7 * N);
}

// Round 5
// 100.574 us; speedup vs baseline: 1.5025x; 1.4732x over previous
//
#include <hip/hip_runtime.h>
#include <math.h>

#define NBATCH 128
#define S 7
#define NCLS 20
#define CH 30
#define N 12544              // 128*7*7*2
#define PERB 98              // boxes per batch (7*7*2)
#define NWORDS 196           // N/64 ballot words
#define NBLK 49              // N/256 decode-domain blocks
#define NCH 16               // chunk rows for k_rankv
#define CSMAX 784            // ceil(N/NCH) -> LDS chunk capacity
#define MAXK 112             // slot stride per batch (>= PERB)
#define THRNMS 0.3

// f32 sigmoid cascade, mirroring numpy float32 ops:
//   e = expf(-x)  (f64 exp rounded once -> correctly-rounded f32 exp)
//   s = 1.0f / (1.0f + e)
__device__ __forceinline__ float sigf(float x) {
    float e = (float)exp(-(double)x);
    return 1.0f / (1.0f + e);
}

// ---------------- decode: per-box record + f32-cascade key + valid ballots ----
__global__ __launch_bounds__(256) void k_decode(
    const float* __restrict__ p,
    unsigned int* __restrict__ key,
    float* __restrict__ score,
    float* __restrict__ box,
    int* __restrict__ meta,
    unsigned long long* __restrict__ ballots)
{
    int i = blockIdx.x * 256 + threadIdx.x;      // grid is exactly N
    int j    = i & 1;
    int cell = i >> 1;
    int x    = cell % S;
    int y    = (cell / S) % S;
    int b    = cell / (S * S);
    const float* pc = p + cell * CH;

    float tx = pc[j * 4 + 0], ty = pc[j * 4 + 1];
    float tw = pc[j * 4 + 2], th = pc[j * 4 + 3];
    float craw = pc[8 + j];

    // first-occurrence argmax over f32-cascade sigmoid(class logits)
    float best = sigf(pc[10]);
    int lab = 0;
#pragma unroll
    for (int c = 1; c < NCLS; ++c) {
        float v = sigf(pc[10 + c]);
        if (v > best) { best = v; lab = c; }
    }
    int label = lab + 1;

    // f32 box geometry in numpy op order
    float sx = sigf(tx), sy = sigf(ty);
    float cx = (sx + (float)x) / 7.0f;
    float cy = (sy + (float)y) / 7.0f;
    float hw = tw / 2.0f, hh = th / 2.0f;
    float l = cx - hw, t = cy - hh, r = cx + hw, bt = cy + hh;

    float sc = sigf(craw);
    bool valid = sc > 0.5f;

    unsigned int k = valid ? __float_as_uint(sc) : 0u;
    key[i] = k;
    score[i] = sc;
    box[i * 4 + 0] = l; box[i * 4 + 1] = t;
    box[i * 4 + 2] = r; box[i * 4 + 3] = bt;
    meta[i] = (valid ? 0x8000 : 0) | (b << 5) | label;

    unsigned long long vb = __ballot(valid);
    if ((threadIdx.x & 63) == 0) ballots[i >> 6] = vb;
}

// ------- tiny scan: block offsets of valid, total nvalid, per-batch counts ----
__global__ __launch_bounds__(256) void k_scan(
    const unsigned long long* __restrict__ ballots,
    unsigned int* __restrict__ blockoff,   // [NBLK] exclusive
    unsigned int* __restrict__ nvalid,     // [1]
    unsigned int* __restrict__ batchcnt)   // [NBATCH]
{
    __shared__ unsigned int bc[NBLK];
    int t = threadIdx.x;
    if (t < NBLK) {
        unsigned int c = 0;
#pragma unroll
        for (int w = 0; w < 4; ++w) c += __popcll(ballots[t * 4 + w]);
        bc[t] = c;
    }
    __syncthreads();
    if (t == 0) {
        unsigned int acc = 0;
        for (int b2 = 0; b2 < NBLK; ++b2) { blockoff[b2] = acc; acc += bc[b2]; }
        *nvalid = acc;
    }
    if (t < NBATCH) {
        int lo = PERB * t, hi = lo + PERB;
        int w0 = lo >> 6, w1 = (hi - 1) >> 6;
        unsigned int c = 0;
        for (int w = w0; w <= w1; ++w) {
            int bitlo = lo - (w << 6); if (bitlo < 0) bitlo = 0;
            int bithi = hi - (w << 6); if (bithi > 64) bithi = 64;
            unsigned long long mask =
                ((bithi >= 64) ? ~0ull : ((1ull << bithi) - 1ull)) &
                ~((1ull << bitlo) - 1ull);
            c += __popcll(ballots[w] & mask);
        }
        batchcnt[t] = c;
    }
}

// ---- compact valids (order-preserving) + emit ALL invalid rows analytically ----
// invalid rank(i) = (N-1-i) + V_inc(i),  V_inc = #valid with index <= i
__global__ __launch_bounds__(256) void k_compact(
    const unsigned long long* __restrict__ ballots,
    const unsigned int* __restrict__ blockoff,
    const unsigned int* __restrict__ key,
    const float* __restrict__ score,
    const float* __restrict__ box,
    const int* __restrict__ meta,
    unsigned int* __restrict__ vkey,
    unsigned int* __restrict__ vidx,
    unsigned int* __restrict__ vrank,
    unsigned int* __restrict__ vbrank,
    float* __restrict__ out)
{
    int i = blockIdx.x * 256 + threadIdx.x;
    int lane = threadIdx.x & 63;
    int wave = threadIdx.x >> 6;
    int wbase = blockIdx.x * 4;

    unsigned int pre = 0;
    for (int w = 0; w < wave; ++w) pre += __popcll(ballots[wbase + w]);
    unsigned long long myb = ballots[wbase + wave];
    unsigned int wpre = __popcll(myb & ((1ull << lane) - 1ull));
    bool valid = (myb >> lane) & 1ull;
    unsigned int Vexc = blockoff[blockIdx.x] + pre + wpre;

    if (valid) {
        unsigned int slot = Vexc;
        vkey[slot] = key[i];
        vidx[slot] = (unsigned int)i;
        vrank[slot] = 0u;
        vbrank[slot] = 0u;
    } else {
        unsigned int pos = (unsigned int)(N - 1 - i) + Vexc;  // V_inc == V_exc
        int m = meta[i];
        int b = (m >> 5) & 0x7F;
        int label = m & 31;
        out[pos] = (float)b;
        out[N + pos * 4 + 0] = box[i * 4 + 0];
        out[N + pos * 4 + 1] = box[i * 4 + 1];
        out[N + pos * 4 + 2] = box[i * 4 + 2];
        out[N + pos * 4 + 3] = box[i * 4 + 3];
        out[5 * N + pos] = (float)label;
        out[6 * N + pos] = score[i];
        out[7 * N + pos] = 0.0f;
    }
}

// ---- rank among valids only (desc key, tie desc slot == desc index) ----
__global__ __launch_bounds__(256) void k_rankv(
    const unsigned int* __restrict__ vkey,
    const unsigned int* __restrict__ vidx,
    const unsigned int* __restrict__ nvalid_p,
    unsigned int* __restrict__ vrank,
    unsigned int* __restrict__ vbrank)
{
    __shared__ uint2 lkb[CSMAX];          // {key, batch}
    unsigned int nv = *nvalid_p;
    if ((unsigned int)(blockIdx.x * 256) >= nv) return;       // block-uniform
    unsigned int cs = (nv + NCH - 1) / NCH;
    unsigned int base = blockIdx.y * cs;
    if (base >= nv) return;                                   // block-uniform
    unsigned int len = cs; if (nv - base < len) len = nv - base;

    for (unsigned int t = threadIdx.x; t < len; t += 256) {
        unsigned int jg = base + t;
        lkb[t] = make_uint2(vkey[jg], vidx[jg] / PERB);
    }
    __syncthreads();

    unsigned int islot = blockIdx.x * 256 + threadIdx.x;
    if (islot < nv) {
        unsigned int ki = vkey[islot];
        unsigned int bi = vidx[islot] / PERB;
        unsigned int cnt = 0, bcnt = 0;
        for (unsigned int u = 0; u < len; ++u) {
            uint2 v = lkb[u];
            unsigned int jg = base + u;
            unsigned int c = (unsigned int)((v.x > ki) || (v.x == ki && jg > islot));
            cnt += c;
            bcnt += c & (unsigned int)(v.y == bi);
        }
        if (cnt)  atomicAdd(&vrank[islot], cnt);
        if (bcnt) atomicAdd(&vbrank[islot], bcnt);
    }
}

// ---- scatter valid rows + per-batch NMS member lists ----
__global__ __launch_bounds__(256) void k_scatterv(
    const unsigned int* __restrict__ vidx,
    const unsigned int* __restrict__ nvalid_p,
    const unsigned int* __restrict__ vrank,
    const unsigned int* __restrict__ vbrank,
    const float* __restrict__ score,
    const float* __restrict__ box,
    const int* __restrict__ meta,
    float4* __restrict__ mbox,
    int* __restrict__ mlab,
    int* __restrict__ mpos,
    float* __restrict__ out)
{
    unsigned int nv = *nvalid_p;
    unsigned int slot = blockIdx.x * 256 + threadIdx.x;
    if (slot >= nv) return;
    unsigned int i = vidx[slot];
    unsigned int pos = vrank[slot];
    int m = meta[i];
    int b = (m >> 5) & 0x7F;
    int label = m & 31;
    float l = box[i * 4 + 0], t = box[i * 4 + 1];
    float r = box[i * 4 + 2], bt = box[i * 4 + 3];

    out[pos] = (float)b;
    out[N + pos * 4 + 0] = l;
    out[N + pos * 4 + 1] = t;
    out[N + pos * 4 + 2] = r;
    out[N + pos * 4 + 3] = bt;
    out[5 * N + pos] = (float)label;
    out[6 * N + pos] = score[i];
    out[7 * N + pos] = 0.0f;                   // keep default; NMS sets 1

    int ms = b * MAXK + (int)vbrank[slot];
    mbox[ms] = make_float4(l, t, r, bt);
    mlab[ms] = label;
    mpos[ms] = (int)pos;
}

// ---------------- greedy NMS: one wave per batch, gather-free ----------------
__global__ __launch_bounds__(64) void k_nms(
    const unsigned int* __restrict__ batchcnt,
    const float4* __restrict__ mbox,
    const int* __restrict__ mlab,
    const int* __restrict__ mpos,
    float* __restrict__ keepout)
{
    int b = blockIdx.x;
    int lane = threadIdx.x;
    __shared__ float bx[MAXK][4];
    __shared__ int lab[MAXK];
    __shared__ int list[MAXK];
    __shared__ int sup[MAXK];

    int k = (int)batchcnt[b];                  // <= 98 structurally
    for (int t = lane; t < k; t += 64) {
        float4 v = mbox[b * MAXK + t];
        bx[t][0] = v.x; bx[t][1] = v.y; bx[t][2] = v.z; bx[t][3] = v.w;
        lab[t] = mlab[b * MAXK + t];
        list[t] = mpos[b * MAXK + t];
        sup[t] = 0;
    }
    __syncthreads();

    for (int i = 0; i < k; ++i) {
        __syncthreads();
        if (sup[i]) continue;                  // uniform broadcast read
        float li = bx[i][0], ti = bx[i][1], ri = bx[i][2], bi = bx[i][3];
        float areai = (ri - li) * (bi - ti);
        int labi = lab[i];
        for (int jj = i + 1 + lane; jj < k; jj += 64) {
            if (lab[jj] != labi) continue;
            float lj = bx[jj][0], tj = bx[jj][1], rj = bx[jj][2], bj = bx[jj][3];
            float lt0 = fmaxf(li, lj), lt1 = fmaxf(ti, tj);
            float rb0 = fminf(ri, rj), rb1 = fminf(bi, bj);
            float w = rb0 - lt0; if (w < 0.0f) w = 0.0f;
            float h = rb1 - lt1; if (h < 0.0f) h = 0.0f;
            float inter = w * h;
            float areaj = (rj - lj) * (bj - tj);
            float uni = areai + areaj - inter;
            double iou = (double)inter / fmax((double)uni, 1e-9);
            if (iou > THRNMS) sup[jj] = 1;
        }
    }
    __syncthreads();

    for (int t = lane; t < k; t += 64) {
        if (!sup[t]) keepout[list[t]] = 1.0f;
    }
}

extern "C" void kernel_launch(void* const* d_in, const int* in_sizes, int n_in,
                              void* d_out, int out_size, void* d_ws, size_t ws_size,
                              hipStream_t stream)
{
    const float* p = (const float*)d_in[0];

    char* w = (char*)d_ws;
    float4* mbox = (float4*)w;                         w += (size_t)NBATCH * MAXK * 16;
    unsigned int* key = (unsigned int*)w;              w += (size_t)N * 4;
    float* score = (float*)w;                          w += (size_t)N * 4;
    float* box   = (float*)w;                          w += (size_t)N * 16;
    int* meta    = (int*)w;                            w += (size_t)N * 4;
    unsigned int* vkey  = (unsigned int*)w;            w += (size_t)N * 4;
    unsigned int* vidx  = (unsigned int*)w;            w += (size_t)N * 4;
    unsigned int* vrank = (unsigned int*)w;            w += (size_t)N * 4;
    unsigned int* vbrank= (unsigned int*)w;            w += (size_t)N * 4;
    unsigned long long* ballots = (unsigned long long*)w; w += (size_t)NWORDS * 8;
    unsigned int* blockoff = (unsigned int*)w;         w += (size_t)NBLK * 4;
    unsigned int* nvalid   = (unsigned int*)w;         w += 4;
    int* mlab    = (int*)w;                            w += (size_t)NBATCH * MAXK * 4;
    int* mpos    = (int*)w;                            w += (size_t)NBATCH * MAXK * 4;
    unsigned int* batchcnt = (unsigned int*)w;         w += (size_t)NBATCH * 4;

    float* out = (float*)d_out;

    k_decode  <<<dim3(NBLK),      dim3(256), 0, stream>>>(p, key, score, box, meta, ballots);
    k_scan    <<<dim3(1),         dim3(256), 0, stream>>>(ballots, blockoff, nvalid, batchcnt);
    k_compact <<<dim3(NBLK),      dim3(256), 0, stream>>>(ballots, blockoff, key, score, box,
                                                          meta, vkey, vidx, vrank, vbrank, out);
    k_rankv   <<<dim3(NBLK, NCH), dim3(256), 0, stream>>>(vkey, vidx, nvalid, vrank, vbrank);
    k_scatterv<<<dim3(NBLK),      dim3(256), 0, stream>>>(vidx, nvalid, vrank, vbrank,
                                                          score, box, meta,
                                                          mbox, mlab, mpos, out);
    k_nms     <<<dim3(NBATCH),    dim3(64),  0, stream>>>(batchcnt, mbox, mlab, mpos,
                                                          out + 7 * N);
}